// Round 5
// baseline (840.391 us; speedup 1.0000x reference)
//
#include <hip/hip_runtime.h>
#include <float.h>

#define NLVL  4
#define KCB   256
#define DIMD  128
#define NROWS 262144
#define WROWS 16             // rows per wave; 1 wave per block, zero barriers
#define MARGIN 0.5f
#define WLCAP 256
#define RING  8              // LDS ring slots, 1KB each (16 entries x 32 k fp16)
#define ADV   7              // chunks in flight (steady-state vmcnt(6))
#define RSTRIDE 132          // fp32 residual-mirror stride (rows 4 banks apart)

typedef _Float16 half8  __attribute__((ext_vector_type(8)));
typedef float    floatx4 __attribute__((ext_vector_type(4)));

// wave-internal phase fence (single-wave blocks: no s_barrier anywhere)
#define WSYNC() asm volatile("s_waitcnt lgkmcnt(0)" ::: "memory")
#define VMW(N)  asm volatile("s_waitcnt vmcnt(" #N ")" ::: "memory")

// async global->LDS, 16B/lane (LDS dest = wave-uniform base + lane*16)
__device__ __forceinline__ void glds16(const void* g, void* l) {
    __builtin_amdgcn_global_load_lds(
        (const __attribute__((address_space(1))) unsigned int*)g,
        (__attribute__((address_space(3))) unsigned int*)l, 16, 0, 0);
}

// ---------------------------------------------------------------------------
// Prep: per-entry ||c||^2 (exact fp32, same fmaf order as always) + linear
// fp16 codebook copy. 1024 entries, thread-per-entry.
// ---------------------------------------------------------------------------
__global__ __launch_bounds__(256) void rq_prep_kernel(const float* __restrict__ cb,
                                                      float* __restrict__ c2,
                                                      _Float16* __restrict__ cbh) {
    int e = blockIdx.x * 256 + threadIdx.x;   // 0..1023
    const float4* p = (const float4*)(cb + (size_t)e * DIMD);
    _Float16* ho = cbh + (size_t)e * DIMD;
    float s = 0.f;
#pragma unroll
    for (int k = 0; k < DIMD / 4; ++k) {
        float4 v = p[k];
        s = fmaf(v.x, v.x, s);
        s = fmaf(v.y, v.y, s);
        s = fmaf(v.z, v.z, s);
        s = fmaf(v.w, v.w, s);
        ho[4 * k + 0] = (_Float16)v.x;
        ho[4 * k + 1] = (_Float16)v.y;
        ho[4 * k + 2] = (_Float16)v.z;
        ho[4 * k + 3] = (_Float16)v.w;
    }
    c2[e] = s;
}

// ---------------------------------------------------------------------------
// Main kernel: 1 wave / 16 rows per block. Residual in 32 VGPRs/lane (MFMA
// A-fragment layout) + fp32 LDS mirror for parallel refinement. Codebook B
// streams through an 8KB LDS ring; staging source is granule-permuted so the
// GEMM ds_read_b128 is LINEAR (lane*16) -> conflict-free. Chunks ordered
// tile-inner so consecutive MFMAs hit different accumulators. 7 chunks in
// flight via counted vmcnt; prefetch never stops across level boundaries.
// ---------------------------------------------------------------------------
__global__ __launch_bounds__(64, 3) void rq_main_kernel(const float* __restrict__ x,
                                                        const float* __restrict__ cb,
                                                        const float* __restrict__ c2g,
                                                        const _Float16* __restrict__ cbh,
                                                        float* __restrict__ out) {
    __shared__ __align__(16) char ring[RING * 1024];            // 8 KB
    __shared__ float res_lds[WROWS * RSTRIDE];                  // 8.25 KB mirror
    __shared__ unsigned int wl[WLCAP];                          // 1 KB
    __shared__ unsigned long long refine_key[WROWS];            // 128 B
    __shared__ int codes_lds[WROWS][4];                         // 256 B
    __shared__ int wl_cnt;

    const int lane = threadIdx.x;          // 64-thread block = 1 wave
    const int q    = lane >> 4;            // 0..3
    const int c    = lane & 15;            // 0..15 (row / entry-column selector)
    const int rowW = blockIdx.x * WROWS;
    // staging role: lane l fetches the granule that lands at LDS offset l*16,
    // i.e. (entry tile*16 + (l&15), k-granule l>>4) -> linear conflict-free read
    const int lane_off = ((lane & 15) << 8) | ((lane >> 4) << 4);
    const char* cbh_b = (const char*)cbh;

    // ---- ring prologue: chunks 0..ADV-1 in flight ----
    // chunk g: level g>>6, within level w=g&63: tile t=w&15, k-step s=w>>4
#pragma unroll
    for (int g = 0; g < ADV; ++g) {
        const char* src = cbh_b + ((g >> 6) << 16) + ((g & 15) << 12)
                        + (((g & 63) >> 4) << 6) + lane_off;
        glds16(src, ring + ((g & (RING - 1)) << 10));
    }

    // ---- stage x -> residual registers (lane(q,c): row c, k=s*32+q*8+j) ----
    float res_[32];
#pragma unroll
    for (int s = 0; s < 4; ++s) {
        const float* px = x + (size_t)(rowW + c) * DIMD + s * 32 + q * 8;
        float4 u = *(const float4*)px;
        float4 v = *(const float4*)(px + 4);
        res_[s*8+0]=u.x; res_[s*8+1]=u.y; res_[s*8+2]=u.z; res_[s*8+3]=u.w;
        res_[s*8+4]=v.x; res_[s*8+5]=v.y; res_[s*8+6]=v.z; res_[s*8+7]=v.w;
    }
    // mirror -> LDS (for parallel refinement)
#pragma unroll
    for (int s = 0; s < 4; ++s) {
        *(float4*)&res_lds[c * RSTRIDE + s * 32 + q * 8] =
            (float4){res_[s*8+0], res_[s*8+1], res_[s*8+2], res_[s*8+3]};
        *(float4*)&res_lds[c * RSTRIDE + s * 32 + q * 8 + 4] =
            (float4){res_[s*8+4], res_[s*8+5], res_[s*8+6], res_[s*8+7]};
    }
    if (lane == 0) wl_cnt = 0;
    if (lane < WROWS) refine_key[lane] = ~0ULL;
    WSYNC();

    for (int l = 0; l < NLVL; ++l) {
        // ---- A fragments from residual regs (layout matches exactly) ----
        half8 a[4];
#pragma unroll
        for (int s = 0; s < 4; ++s)
#pragma unroll
            for (int j = 0; j < 8; ++j)
                a[s][j] = (_Float16)res_[s * 8 + j];

        floatx4 acc[16];
#pragma unroll
        for (int t = 0; t < 16; ++t) acc[t] = (floatx4){0.f, 0.f, 0.f, 0.f};

        // ---- streamed GEMM: 64 chunks, tile-inner order (t=w&15, s=w>>4) ----
#pragma unroll
        for (int w = 0; w < 64; ++w) {
            if      (w <  58) VMW(6);      // steady state: 6 newer chunks in flight
            else if (w == 58) VMW(5);      // taper (covers last level's tail)
            else if (w == 59) VMW(4);
            else if (w == 60) VMW(3);
            else if (w == 61) VMW(2);
            else if (w == 62) VMW(1);
            else              VMW(0);
            // linear, conflict-free B read: lane l's fragment at slot + l*16
            half8 b = *(const half8*)(ring + ((w & (RING - 1)) << 10) + (lane << 4));
            if (l < NLVL - 1 || w < 64 - ADV) {     // continuous cross-level prefetch
                int g2 = l * 64 + w + ADV;
                const char* src = cbh_b + ((g2 >> 6) << 16) + ((g2 & 15) << 12)
                                + (((g2 & 63) >> 4) << 6) + lane_off;
                glds16(src, ring + ((g2 & (RING - 1)) << 10));
            }
            acc[w & 15] = __builtin_amdgcn_mfma_f32_16x16x32_f16(a[w >> 4], b, acc[w & 15], 0, 0, 0);
        }

        // per-lane c2 for my 16 candidate entries (loaded late: short live range)
        float c2v[16];
#pragma unroll
        for (int t = 0; t < 16; ++t) c2v[t] = c2g[l * KCB + t * 16 + c];

        // ---- selection: argmin + margin filter (identical logic to R0) ----
#pragma unroll
        for (int r = 0; r < 4; ++r) {
            float bv = FLT_MAX; int be = 0;
#pragma unroll
            for (int t = 0; t < 16; ++t) {
                float d = c2v[t] - 2.f * acc[t][r];
                if (d < bv) { bv = d; be = t * 16 + c; }
            }
#pragma unroll
            for (int m = 1; m < 16; m <<= 1) {
                float ov = __shfl_xor(bv, m);
                int   oe = __shfl_xor(be, m);
                if (ov < bv || (ov == bv && oe < be)) { bv = ov; be = oe; }
            }
            float thr = bv + MARGIN;
            int cnt = 0;
#pragma unroll
            for (int t = 0; t < 16; ++t)
                cnt += (c2v[t] - 2.f * acc[t][r]) <= thr;
#pragma unroll
            for (int m = 1; m < 16; m <<= 1) cnt += __shfl_xor(cnt, m);

            int row_m = q * 4 + r;
            if (c == 0) codes_lds[row_m][l] = be;
            if (cnt >= 2) {
#pragma unroll
                for (int t = 0; t < 16; ++t) {
                    float d = c2v[t] - 2.f * acc[t][r];
                    if (d <= thr) {
                        int slot = atomicAdd(&wl_cnt, 1);
                        if (slot < WLCAP)
                            wl[slot] = ((unsigned)row_m << 8) | (unsigned)(t * 16 + c);
                    }
                }
            }
        }
        WSYNC();

        // ---- exact fp32 refinement, PARALLEL (lane-per-candidate), residual
        //      from LDS mirror; same serial fmaf k-order as the reference path ----
        int n = wl_cnt; if (n > WLCAP) n = WLCAP;
        for (int i = lane; i < n; i += 64) {
            unsigned int it = wl[i];
            int row_m = (int)(it >> 8), e = (int)(it & 255u);
            const float* rr = &res_lds[row_m * RSTRIDE];
            const float* cc = cb + ((size_t)l * KCB + e) * DIMD;
            float d = 0.f;
#pragma unroll
            for (int k = 0; k < DIMD / 4; ++k) {
                float4 rv = *(const float4*)(rr + 4 * k);
                float4 cv = *(const float4*)(cc + 4 * k);
                d = fmaf(rv.x, cv.x, d);
                d = fmaf(rv.y, cv.y, d);
                d = fmaf(rv.z, cv.z, d);
                d = fmaf(rv.w, cv.w, d);
            }
            float dist = c2g[l * KCB + e] - 2.f * d;
            unsigned int ob = __float_as_uint(dist);
            ob = (ob & 0x80000000u) ? ~ob : (ob | 0x80000000u);
            unsigned long long key = ((unsigned long long)ob << 32) | (unsigned int)e;
            atomicMin(&refine_key[row_m], key);
        }
        WSYNC();

        // ---- residual update in registers (exact fp32) + mirror refresh ----
        {
            unsigned long long k = refine_key[c];
            int idx = (k != ~0ULL) ? (int)(k & 0xFFFFFFFFULL) : codes_lds[c][l];
            if (q == 0) codes_lds[c][l] = idx;
            const float* cbase = cb + ((size_t)l * KCB + idx) * DIMD + q * 8;
#pragma unroll
            for (int s = 0; s < 4; ++s) {
                float4 u = *(const float4*)(cbase + s * 32);
                float4 v = *(const float4*)(cbase + s * 32 + 4);
                res_[s*8+0] -= u.x; res_[s*8+1] -= u.y;
                res_[s*8+2] -= u.z; res_[s*8+3] -= u.w;
                res_[s*8+4] -= v.x; res_[s*8+5] -= v.y;
                res_[s*8+6] -= v.z; res_[s*8+7] -= v.w;
            }
            if (l < NLVL - 1) {
#pragma unroll
                for (int s = 0; s < 4; ++s) {
                    *(float4*)&res_lds[c * RSTRIDE + s * 32 + q * 8] =
                        (float4){res_[s*8+0], res_[s*8+1], res_[s*8+2], res_[s*8+3]};
                    *(float4*)&res_lds[c * RSTRIDE + s * 32 + q * 8 + 4] =
                        (float4){res_[s*8+4], res_[s*8+5], res_[s*8+6], res_[s*8+7]};
                }
            }
        }
        if (lane == 0) wl_cnt = 0;
        if (lane < WROWS) refine_key[lane] = ~0ULL;
        WSYNC();
    }

    // ---- output: recon = x - residual; codes as float4/row ----
#pragma unroll
    for (int s = 0; s < 4; ++s) {
        const float* px = x + (size_t)(rowW + c) * DIMD + s * 32 + q * 8;
        float4 u = *(const float4*)px;
        float4 v = *(const float4*)(px + 4);
        float4 o0, o1;
        o0.x = u.x - res_[s*8+0]; o0.y = u.y - res_[s*8+1];
        o0.z = u.z - res_[s*8+2]; o0.w = u.w - res_[s*8+3];
        o1.x = v.x - res_[s*8+4]; o1.y = v.y - res_[s*8+5];
        o1.z = v.z - res_[s*8+6]; o1.w = v.w - res_[s*8+7];
        float* po = out + (size_t)(rowW + c) * DIMD + s * 32 + q * 8;
        *(float4*)po = o0;
        *(float4*)(po + 4) = o1;
    }
    if (lane < WROWS) {
        float4 cd;
        cd.x = (float)codes_lds[lane][0];
        cd.y = (float)codes_lds[lane][1];
        cd.z = (float)codes_lds[lane][2];
        cd.w = (float)codes_lds[lane][3];
        ((float4*)(out + (size_t)NROWS * DIMD))[rowW + lane] = cd;
    }
}

extern "C" void kernel_launch(void* const* d_in, const int* in_sizes, int n_in,
                              void* d_out, int out_size, void* d_ws, size_t ws_size,
                              hipStream_t stream) {
    const float* x  = (const float*)d_in[0];
    const float* cb = (const float*)d_in[1];
    float* out = (float*)d_out;

    float*    c2  = (float*)d_ws;                        // 4096 floats = 16 KB
    _Float16* cbh = (_Float16*)((char*)d_ws + 16384);    // 256 KB fp16 codebook (linear)

    rq_prep_kernel<<<NLVL * KCB / 256, 256, 0, stream>>>(cb, c2, cbh);
    rq_main_kernel<<<NROWS / WROWS, 64, 0, stream>>>(x, cb, c2, cbh, out);
}

// Round 6
// 802.266 us; speedup vs baseline: 1.0475x; 1.0475x over previous
//
#include <hip/hip_runtime.h>
#include <float.h>

#define NLVL  4
#define KCB   256
#define DIMD  128
#define NROWS 262144
#define WROWS 16             // rows per wave; 1 wave per block, zero barriers
#define MARGIN 0.5f
#define WLROW 24             // per-row refinement candidate cap
#define RING  8              // LDS ring slots, 1KB each (16 entries x 32 k fp16)
#define ADV   7              // chunks in flight (steady-state vmcnt(6))

typedef _Float16 half8  __attribute__((ext_vector_type(8)));
typedef float    floatx4 __attribute__((ext_vector_type(4)));

// wave-internal phase fence (single-wave blocks: no s_barrier anywhere)
#define WSYNC() asm volatile("s_waitcnt lgkmcnt(0)" ::: "memory")
#define VMW(N)  asm volatile("s_waitcnt vmcnt(" #N ")" ::: "memory")

// async global->LDS, 16B/lane (LDS dest = wave-uniform base + lane*16)
__device__ __forceinline__ void glds16(const void* g, void* l) {
    __builtin_amdgcn_global_load_lds(
        (const __attribute__((address_space(1))) unsigned int*)g,
        (__attribute__((address_space(3))) unsigned int*)l, 16, 0, 0);
}

// ---------------------------------------------------------------------------
// Prep: per-entry ||c||^2 (exact fp32, same fmaf order as always) + linear
// fp16 codebook copy. 1024 entries, thread-per-entry.
// ---------------------------------------------------------------------------
__global__ __launch_bounds__(256) void rq_prep_kernel(const float* __restrict__ cb,
                                                      float* __restrict__ c2,
                                                      _Float16* __restrict__ cbh) {
    int e = blockIdx.x * 256 + threadIdx.x;   // 0..1023
    const float4* p = (const float4*)(cb + (size_t)e * DIMD);
    _Float16* ho = cbh + (size_t)e * DIMD;
    float s = 0.f;
#pragma unroll
    for (int k = 0; k < DIMD / 4; ++k) {
        float4 v = p[k];
        s = fmaf(v.x, v.x, s);
        s = fmaf(v.y, v.y, s);
        s = fmaf(v.z, v.z, s);
        s = fmaf(v.w, v.w, s);
        ho[4 * k + 0] = (_Float16)v.x;
        ho[4 * k + 1] = (_Float16)v.y;
        ho[4 * k + 2] = (_Float16)v.z;
        ho[4 * k + 3] = (_Float16)v.w;
    }
    c2[e] = s;
}

// ---------------------------------------------------------------------------
// Main kernel: 1 wave / 16 rows per block. Residual in 32 VGPRs/lane (MFMA
// A-fragment layout: lane(q,c) holds row c, k = s*32+q*8+j). Codebook B
// streams through an 8KB LDS ring with source-permuted granules so the GEMM
// ds_read_b128 is LINEAR (lane*16, conflict-free); tile-inner chunk order so
// consecutive MFMAs hit different accumulators. Refinement is column-grouped:
// the 4 q-lanes owning a row walk that row's candidate list using their
// register residual slices + shfl_xor reduce (no LDS mirror -> 9.8KB LDS,
// occupancy restored). Zero barriers; counted vmcnt keeps 7 chunks in flight,
// tapering only inside the last level.
// ---------------------------------------------------------------------------
__global__ __launch_bounds__(64, 3) void rq_main_kernel(const float* __restrict__ x,
                                                        const float* __restrict__ cb,
                                                        const float* __restrict__ c2g,
                                                        const _Float16* __restrict__ cbh,
                                                        float* __restrict__ out) {
    __shared__ __align__(16) char ring[RING * 1024];            // 8 KB
    __shared__ unsigned int wl_row[WROWS][WLROW];               // 1.5 KB
    __shared__ int wl_cnt_row[WROWS];                           // 64 B

    const int lane = threadIdx.x;          // 64-thread block = 1 wave
    const int q    = lane >> 4;            // 0..3
    const int c    = lane & 15;            // 0..15 (row / entry-column selector)
    const int rowW = blockIdx.x * WROWS;
    // staging role: lane l fetches the granule that lands at LDS offset l*16,
    // i.e. entry (l&15) of the tile, k-granule (l>>4) -> linear conflict-free read
    const int lane_off = ((lane & 15) << 8) | ((lane >> 4) << 4);
    const char* cbh_b = (const char*)cbh;

    // ---- ring prologue: chunks 0..ADV-1 in flight ----
    // chunk g: level g>>6; within level w=g&63: tile t=w&15, k-step s=w>>4
#pragma unroll
    for (int g = 0; g < ADV; ++g) {
        const char* src = cbh_b + ((g >> 6) << 16) + ((g & 15) << 12)
                        + (((g & 63) >> 4) << 6) + lane_off;
        glds16(src, ring + ((g & (RING - 1)) << 10));
    }

    // ---- stage x -> residual registers ----
    float res_[32];
#pragma unroll
    for (int s = 0; s < 4; ++s) {
        const float* px = x + (size_t)(rowW + c) * DIMD + s * 32 + q * 8;
        float4 u = *(const float4*)px;
        float4 v = *(const float4*)(px + 4);
        res_[s*8+0]=u.x; res_[s*8+1]=u.y; res_[s*8+2]=u.z; res_[s*8+3]=u.w;
        res_[s*8+4]=v.x; res_[s*8+5]=v.y; res_[s*8+6]=v.z; res_[s*8+7]=v.w;
    }
    if (lane < WROWS) wl_cnt_row[lane] = 0;
    WSYNC();

    int code0 = 0, code1 = 0, code2 = 0, code3 = 0;   // codes for row c (per-lane)

#pragma unroll
    for (int l = 0; l < NLVL; ++l) {
        // ---- A fragments from residual regs (layout matches exactly) ----
        half8 a[4];
#pragma unroll
        for (int s = 0; s < 4; ++s)
#pragma unroll
            for (int j = 0; j < 8; ++j)
                a[s][j] = (_Float16)res_[s * 8 + j];

        floatx4 acc[16];
#pragma unroll
        for (int t = 0; t < 16; ++t) acc[t] = (floatx4){0.f, 0.f, 0.f, 0.f};

        // ---- streamed GEMM: 64 chunks, tile-inner order (t=w&15, s=w>>4) ----
#pragma unroll
        for (int w = 0; w < 64; ++w) {
            if (l == NLVL - 1) {               // taper only inside the last level
                if      (w <  58) VMW(6);
                else if (w == 58) VMW(5);
                else if (w == 59) VMW(4);
                else if (w == 60) VMW(3);
                else if (w == 61) VMW(2);
                else if (w == 62) VMW(1);
                else              VMW(0);
            } else {
                VMW(6);                        // steady state: 6 newer chunks in flight
            }
            // linear, conflict-free B read: lane l's fragment at slot + l*16
            half8 b = *(const half8*)(ring + ((w & (RING - 1)) << 10) + (lane << 4));
            if (l < NLVL - 1 || w < 64 - ADV) {     // continuous cross-level prefetch
                int g2 = l * 64 + w + ADV;
                const char* src = cbh_b + ((g2 >> 6) << 16) + ((g2 & 15) << 12)
                                + (((g2 & 63) >> 4) << 6) + lane_off;
                glds16(src, ring + ((g2 & (RING - 1)) << 10));
            }
            acc[w & 15] = __builtin_amdgcn_mfma_f32_16x16x32_f16(a[w >> 4], b, acc[w & 15], 0, 0, 0);
        }

        // per-lane c2 for my 16 candidate entries (loaded late: short live range)
        float c2v[16];
#pragma unroll
        for (int t = 0; t < 16; ++t) c2v[t] = c2g[l * KCB + t * 16 + c];

        // ---- selection: argmin + margin filter; per-row worklists ----
        int be0 = 0, be1 = 0, be2 = 0, be3 = 0;   // MFMA argmin for rows q*4+r
#pragma unroll
        for (int r = 0; r < 4; ++r) {
            float bv = FLT_MAX; int be = 0;
#pragma unroll
            for (int t = 0; t < 16; ++t) {
                float d = c2v[t] - 2.f * acc[t][r];
                if (d < bv) { bv = d; be = t * 16 + c; }
            }
#pragma unroll
            for (int m = 1; m < 16; m <<= 1) {
                float ov = __shfl_xor(bv, m);
                int   oe = __shfl_xor(be, m);
                if (ov < bv || (ov == bv && oe < be)) { bv = ov; be = oe; }
            }
            if      (r == 0) be0 = be;
            else if (r == 1) be1 = be;
            else if (r == 2) be2 = be;
            else             be3 = be;

            float thr = bv + MARGIN;
            int cnt = 0;
#pragma unroll
            for (int t = 0; t < 16; ++t)
                cnt += (c2v[t] - 2.f * acc[t][r]) <= thr;
#pragma unroll
            for (int m = 1; m < 16; m <<= 1) cnt += __shfl_xor(cnt, m);

            int row_m = q * 4 + r;
            if (cnt >= 2) {
#pragma unroll
                for (int t = 0; t < 16; ++t) {
                    float d = c2v[t] - 2.f * acc[t][r];
                    if (d <= thr) {
                        int slot = atomicAdd(&wl_cnt_row[row_m], 1);
                        if (slot < WLROW)
                            wl_row[row_m][slot] = (unsigned)(t * 16 + c);
                    }
                }
            }
        }
        WSYNC();

        // ---- MFMA-argmin fallback for MY row c (reach the column group) ----
        int src_l = ((c >> 2) << 4) | c;          // a lane with q = c>>2
        int f0 = __shfl(be0, src_l), f1 = __shfl(be1, src_l);
        int f2 = __shfl(be2, src_l), f3 = __shfl(be3, src_l);
        int rsel = c & 3;
        int se = f0;
        se = (rsel == 1) ? f1 : se;
        se = (rsel == 2) ? f2 : se;
        se = (rsel == 3) ? f3 : se;

        // ---- exact fp32 refinement: 4 q-lanes of column c walk row c's list,
        //      residual straight from registers, shfl_xor reduce over q ----
        unsigned long long bk = ~0ULL;
        int nc = wl_cnt_row[c]; if (nc > WLROW) nc = WLROW;
        for (int i = 0; i < nc; ++i) {
            int e = (int)wl_row[c][i];
            const float* cc = cb + ((size_t)l * KCB + e) * DIMD;
            float d = 0.f;
#pragma unroll
            for (int s = 0; s < 4; ++s) {
                const float* cp = cc + s * 32 + q * 8;
                float4 u = *(const float4*)cp;
                float4 v = *(const float4*)(cp + 4);
                d = fmaf(res_[s*8+0], u.x, d); d = fmaf(res_[s*8+1], u.y, d);
                d = fmaf(res_[s*8+2], u.z, d); d = fmaf(res_[s*8+3], u.w, d);
                d = fmaf(res_[s*8+4], v.x, d); d = fmaf(res_[s*8+5], v.y, d);
                d = fmaf(res_[s*8+6], v.z, d); d = fmaf(res_[s*8+7], v.w, d);
            }
            d += __shfl_xor(d, 16);               // partners share column c: safe
            d += __shfl_xor(d, 32);
            float dist = c2g[l * KCB + e] - 2.f * d;
            unsigned int ob = __float_as_uint(dist);
            ob = (ob & 0x80000000u) ? ~ob : (ob | 0x80000000u);
            unsigned long long key = ((unsigned long long)ob << 32) | (unsigned int)e;
            bk = (key < bk) ? key : bk;
        }
        int idx = (bk != ~0ULL) ? (int)(bk & 0xFFFFFFFFULL) : se;
        if      (l == 0) code0 = idx;
        else if (l == 1) code1 = idx;
        else if (l == 2) code2 = idx;
        else             code3 = idx;

        // ---- residual update in registers (exact fp32) ----
        {
            const float* cbase = cb + ((size_t)l * KCB + idx) * DIMD + q * 8;
#pragma unroll
            for (int s = 0; s < 4; ++s) {
                float4 u = *(const float4*)(cbase + s * 32);
                float4 v = *(const float4*)(cbase + s * 32 + 4);
                res_[s*8+0] -= u.x; res_[s*8+1] -= u.y;
                res_[s*8+2] -= u.z; res_[s*8+3] -= u.w;
                res_[s*8+4] -= v.x; res_[s*8+5] -= v.y;
                res_[s*8+6] -= v.z; res_[s*8+7] -= v.w;
            }
        }
        // reset per-row counters for next level (wave LDS ops are in-order)
        if (lane < WROWS) wl_cnt_row[lane] = 0;
        WSYNC();
    }

    // ---- output: recon = x - residual; codes as float4/row ----
#pragma unroll
    for (int s = 0; s < 4; ++s) {
        const float* px = x + (size_t)(rowW + c) * DIMD + s * 32 + q * 8;
        float4 u = *(const float4*)px;
        float4 v = *(const float4*)(px + 4);
        float4 o0, o1;
        o0.x = u.x - res_[s*8+0]; o0.y = u.y - res_[s*8+1];
        o0.z = u.z - res_[s*8+2]; o0.w = u.w - res_[s*8+3];
        o1.x = v.x - res_[s*8+4]; o1.y = v.y - res_[s*8+5];
        o1.z = v.z - res_[s*8+6]; o1.w = v.w - res_[s*8+7];
        float* po = out + (size_t)(rowW + c) * DIMD + s * 32 + q * 8;
        *(float4*)po = o0;
        *(float4*)(po + 4) = o1;
    }
    if (lane < WROWS) {   // these lanes have q==0, c==lane -> own row lane's codes
        float4 cd;
        cd.x = (float)code0; cd.y = (float)code1;
        cd.z = (float)code2; cd.w = (float)code3;
        ((float4*)(out + (size_t)NROWS * DIMD))[rowW + lane] = cd;
    }
}

extern "C" void kernel_launch(void* const* d_in, const int* in_sizes, int n_in,
                              void* d_out, int out_size, void* d_ws, size_t ws_size,
                              hipStream_t stream) {
    const float* x  = (const float*)d_in[0];
    const float* cb = (const float*)d_in[1];
    float* out = (float*)d_out;

    float*    c2  = (float*)d_ws;                        // 4096 floats = 16 KB
    _Float16* cbh = (_Float16*)((char*)d_ws + 16384);    // 256 KB fp16 codebook (linear)

    rq_prep_kernel<<<NLVL * KCB / 256, 256, 0, stream>>>(cb, c2, cbh);
    rq_main_kernel<<<NROWS / WROWS, 64, 0, stream>>>(x, cb, c2, cbh, out);
}